// Round 12
// baseline (111.116 us; speedup 1.0000x reference)
//
#include <hip/hip_runtime.h>

// Problem constants (match reference)
#define DEPTH     257    // 256 train ids + OOV
#define OUT_DIM   64
#define OOV_B     256
#define LUT_SIZE  512
#define TAB_QUADS (DEPTH * 16)     // 4112 f32x4 = 65,792 B (bucket-space table)
#define BLOCK     1024
#define GRID      256              // 1 block/CU
#define ROWS_PER_BLK 8192          // contiguous slab per block (2 MB output)
#define ROWS_PER_WAVE 512          // contiguous sub-slab per wave (128 KB output)
#define WSTEPS    128              // 512 rows / 4 rows-per-step

typedef float f32x4 __attribute__((ext_vector_type(4)));

// R11 retry (fixed j increment: 16 rows = 256 quads per x4 body; R11's 1024
// overran each wave's sub-slab 4x and stored past d_out -> crash).
// PER-WAVE contiguous sub-slabs: wave w owns rows [w*512,(w+1)*512) of the
// block slab and walks its 128 KB strictly sequentially (1 KB per store,
// 4 KB per body). Every wave on the chip is a monotone sequential writer
// independent of scheduling drift.
__global__ __launch_bounds__(BLOCK) void onehot_waveslab_kernel(
        const float* __restrict__ raw_ids,
        const float* __restrict__ W,
        const int* __restrict__ lut,
        f32x4* __restrict__ out4,
        int total_quads) {
    __shared__ f32x4 sTab[TAB_QUADS];        // 65,792 B
    __shared__ float sIds[ROWS_PER_BLK];     // 32,768 B
    __shared__ int   sLut[LUT_SIZE + 1];     //  2,052 B
    __shared__ int   sOk;

    if (threadIdx.x == 0) sOk = 1;
    __syncthreads();

    const int fastShape = (total_quads == GRID * ROWS_PER_BLK * 16);

    // ---- stage this block's contiguous id slab (32 KB, coalesced float4) ----
    if (fastShape) {
        const float4* raw4 = (const float4*)raw_ids;
        float4* sIds4 = (float4*)sIds;
        #pragma unroll
        for (int i = 0; i < 2; ++i) {
            int k = threadIdx.x + i * BLOCK;                 // 0..2047
            sIds4[k] = raw4[blockIdx.x * (ROWS_PER_BLK / 4) + k];
        }
    }
    // ---- stage lut + verify identity-min structure ----
    for (int k = threadIdx.x; k <= LUT_SIZE; k += BLOCK) {
        int v = (k < LUT_SIZE) ? lut[k] : OOV_B;
        sLut[k] = v;
        if (v != min(k, OOV_B)) sOk = 0;     // benign race: only 0 written
    }
    // ---- stage W.T bucket table (scalar L2 gathers, one-time) ----
    for (int k = threadIdx.x; k < TAB_QUADS; k += BLOCK) {
        int b  = k >> 4;                     // bucket 0..256
        int qq = k & 15;
        f32x4 v;
        v.x = W[(4 * qq + 0) * DEPTH + b];
        v.y = W[(4 * qq + 1) * DEPTH + b];
        v.z = W[(4 * qq + 2) * DEPTH + b];
        v.w = W[(4 * qq + 3) * DEPTH + b];
        sTab[k] = v;
    }
    __syncthreads();

    const bool fast = (sOk != 0);            // block-uniform
    const int w    = threadIdx.x >> 6;       // wave 0..15
    const int lane = threadIdx.x & 63;
    const int lr   = lane >> 4;              // row-in-group 0..3
    const int q    = lane & 15;              // quad within row

    if (fastShape && fast) {
        // Wave-sequential walk: each x4 body covers 16 consecutive rows
        // (4 row-groups of 4 rows); j advances 256 quads (= 16 rows) per
        // body. 32 bodies cover the wave's 512 rows.
        const int row0 = w * ROWS_PER_WAVE;              // within block slab
        int j = (blockIdx.x * ROWS_PER_BLK + row0 + lr) * 16 + q;
        #pragma unroll 1
        for (int s = 0; s < WSTEPS; s += 4, j += 256) {
            float f0 = sIds[row0 + 4 * s + 0  + lr];
            float f1 = sIds[row0 + 4 * s + 4  + lr];
            float f2 = sIds[row0 + 4 * s + 8  + lr];
            float f3 = sIds[row0 + 4 * s + 12 + lr];
            unsigned u0 = min((unsigned)__float2int_rn(f0), (unsigned)OOV_B);
            unsigned u1 = min((unsigned)__float2int_rn(f1), (unsigned)OOV_B);
            unsigned u2 = min((unsigned)__float2int_rn(f2), (unsigned)OOV_B);
            unsigned u3 = min((unsigned)__float2int_rn(f3), (unsigned)OOV_B);
            f32x4 v0 = sTab[u0 * 16 + q];
            f32x4 v1 = sTab[u1 * 16 + q];
            f32x4 v2 = sTab[u2 * 16 + q];
            f32x4 v3 = sTab[u3 * 16 + q];
            out4[j]       = v0;              // rows +0,+4,+8,+12 of this group:
            out4[j + 64]  = v1;              // body writes 4 KB contiguous
            out4[j + 128] = v2;
            out4[j + 192] = v3;
        }
    } else {
        // Generic path (any shape / any lut): ids from global, two-hop map.
        const int stride = GRID * BLOCK;
        for (int j = blockIdx.x * BLOCK + threadIdx.x; j < total_quads;
             j += stride) {
            unsigned i = min((unsigned)__float2int_rn(raw_ids[j >> 4]),
                             (unsigned)LUT_SIZE);
            unsigned b = min((unsigned)sLut[i], (unsigned)OOV_B);
            out4[j] = sTab[b * 16 + (j & 15)];
        }
    }
}

extern "C" void kernel_launch(void* const* d_in, const int* in_sizes, int n_in,
                              void* d_out, int out_size, void* d_ws,
                              size_t ws_size, hipStream_t stream) {
    const float* raw_ids = (const float*)d_in[0];   // [N] f32 (integral values)
    const float* W       = (const float*)d_in[1];   // [64][257] f32
    const int*   lut     = (const int*)d_in[2];     // [512] i32
    float*       out     = (float*)d_out;           // [N][64] f32
    (void)d_ws; (void)ws_size;

    const int n = in_sizes[0];                      // 2,097,152
    const int total_quads = n * (OUT_DIM / 4);      // 33,554,432

    onehot_waveslab_kernel<<<GRID, BLOCK, 0, stream>>>(
        raw_ids, W, lut, (f32x4*)out, total_quads);
}

// Round 13
// 102.280 us; speedup vs baseline: 1.0864x; 1.0864x over previous
//
#include <hip/hip_runtime.h>

// Problem constants (match reference)
#define DEPTH     257    // 256 train ids + OOV
#define OUT_DIM   64
#define OOV_B     256
#define LUT_SIZE  512
#define TAB_QUADS (DEPTH * 16)     // 4112 f32x4 = 65,792 B (bucket-space table)
#define BLOCK     1024
#define GRID      256              // 1 block/CU
#define STEPS     128              // steps per block: 8192 rows / 64 rows-per-step
#define ROWS_PER_BLK 8192          // contiguous slab per block (2 MB output)

typedef float f32x4 __attribute__((ext_vector_type(4)));

// SESSION BEST (R10, 102.3 us = 5.4 TB/s effective): contiguous-slab output
// mapping. Block b owns rows [b*8192,(b+1)*8192) and walks its 2 MB slab
// SEQUENTIALLY (16 KB per step) — per-CU monotone write stream, maximal DRAM
// page locality. Ids staged in LDS (pure-write hot loop); W.T bucket table
// in LDS; bucket(id)==min(id,256) verified at runtime (generic sLut fallback
// for arbitrary lut). Levers tested & rejected: 2 blocks/CU, SW pipelining,
// NT stores, per-wave sub-slabs.
__global__ __launch_bounds__(BLOCK) void onehot_slab_kernel(
        const float* __restrict__ raw_ids,
        const float* __restrict__ W,
        const int* __restrict__ lut,
        f32x4* __restrict__ out4,
        int total_quads) {
    __shared__ f32x4 sTab[TAB_QUADS];        // 65,792 B
    __shared__ float sIds[ROWS_PER_BLK];     // 32,768 B
    __shared__ int   sLut[LUT_SIZE + 1];     //  2,052 B
    __shared__ int   sOk;

    if (threadIdx.x == 0) sOk = 1;
    __syncthreads();

    const int fastShape = (total_quads == GRID * ROWS_PER_BLK * 16);

    // ---- stage this block's contiguous id slab (32 KB, coalesced float4) ----
    if (fastShape) {
        const float4* raw4 = (const float4*)raw_ids;
        float4* sIds4 = (float4*)sIds;
        #pragma unroll
        for (int i = 0; i < 2; ++i) {
            int k = threadIdx.x + i * BLOCK;                 // 0..2047
            sIds4[k] = raw4[blockIdx.x * (ROWS_PER_BLK / 4) + k];
        }
    }
    // ---- stage lut + verify identity-min structure ----
    for (int k = threadIdx.x; k <= LUT_SIZE; k += BLOCK) {
        int v = (k < LUT_SIZE) ? lut[k] : OOV_B;
        sLut[k] = v;
        if (v != min(k, OOV_B)) sOk = 0;     // benign race: only 0 written
    }
    // ---- stage W.T bucket table (scalar L2 gathers, one-time) ----
    for (int k = threadIdx.x; k < TAB_QUADS; k += BLOCK) {
        int b  = k >> 4;                     // bucket 0..256
        int qq = k & 15;
        f32x4 v;
        v.x = W[(4 * qq + 0) * DEPTH + b];
        v.y = W[(4 * qq + 1) * DEPTH + b];
        v.z = W[(4 * qq + 2) * DEPTH + b];
        v.w = W[(4 * qq + 3) * DEPTH + b];
        sTab[k] = v;
    }
    __syncthreads();

    const bool fast = (sOk != 0);            // block-uniform
    const int q = threadIdx.x & 15;          // quad within row
    const int r = threadIdx.x >> 4;          // row-in-step 0..63

    if (fastShape && fast) {
        // Sequential slab walk: j advances +1024 quads (16 KB) per step.
        // Wave store = 4 consecutive rows = 1 KB contiguous; block step =
        // 64 rows = 16 KB contiguous; whole block = 2 MB monotone stream.
        int j = blockIdx.x * (ROWS_PER_BLK * 16) + threadIdx.x;
        #pragma unroll 1
        for (int m = 0; m < STEPS; m += 4, j += 4 * BLOCK) {
            float f0 = sIds[(m + 0) * 64 + r];
            float f1 = sIds[(m + 1) * 64 + r];
            float f2 = sIds[(m + 2) * 64 + r];
            float f3 = sIds[(m + 3) * 64 + r];
            unsigned u0 = min((unsigned)__float2int_rn(f0), (unsigned)OOV_B);
            unsigned u1 = min((unsigned)__float2int_rn(f1), (unsigned)OOV_B);
            unsigned u2 = min((unsigned)__float2int_rn(f2), (unsigned)OOV_B);
            unsigned u3 = min((unsigned)__float2int_rn(f3), (unsigned)OOV_B);
            f32x4 v0 = sTab[u0 * 16 + q];
            f32x4 v1 = sTab[u1 * 16 + q];
            f32x4 v2 = sTab[u2 * 16 + q];
            f32x4 v3 = sTab[u3 * 16 + q];
            out4[j]             = v0;
            out4[j + BLOCK]     = v1;
            out4[j + 2 * BLOCK] = v2;
            out4[j + 3 * BLOCK] = v3;
        }
    } else {
        // Generic path (any shape / any lut): ids from global, two-hop map.
        const int stride = GRID * BLOCK;
        for (int j = blockIdx.x * BLOCK + threadIdx.x; j < total_quads;
             j += stride) {
            unsigned i = min((unsigned)__float2int_rn(raw_ids[j >> 4]),
                             (unsigned)LUT_SIZE);
            unsigned b = min((unsigned)sLut[i], (unsigned)OOV_B);
            out4[j] = sTab[b * 16 + (j & 15)];
        }
    }
}

extern "C" void kernel_launch(void* const* d_in, const int* in_sizes, int n_in,
                              void* d_out, int out_size, void* d_ws,
                              size_t ws_size, hipStream_t stream) {
    const float* raw_ids = (const float*)d_in[0];   // [N] f32 (integral values)
    const float* W       = (const float*)d_in[1];   // [64][257] f32
    const int*   lut     = (const int*)d_in[2];     // [512] i32
    float*       out     = (float*)d_out;           // [N][64] f32
    (void)d_ws; (void)ws_size;

    const int n = in_sizes[0];                      // 2,097,152
    const int total_quads = n * (OUT_DIM / 4);      // 33,554,432

    onehot_slab_kernel<<<GRID, BLOCK, 0, stream>>>(
        raw_ids, W, lut, (f32x4*)out, total_quads);
}